// Round 2
// baseline (1057.431 us; speedup 1.0000x reference)
//
#include <hip/hip_runtime.h>
#include <hip/hip_bf16.h>
#include <math.h>

// B=128, N=2048, C=256, H=8, KD=VD=32, OUT=256
// Inputs (fp32): q_data[B,N,C], m_data[B,N,C], q_mask[B,N,1], bias(unused),
//   query_w[C,H,KD], key_w[C,KD], value_w[C,VD], gating_w[C,H,VD],
//   gating_b[H,VD], output_w[H,VD,OUT], output_b[OUT]
// Output fp32 [B,N,OUT]

typedef unsigned short u16;
typedef u16 us4 __attribute__((ext_vector_type(4)));
typedef short bf16x8 __attribute__((ext_vector_type(8)));
typedef float f32x4 __attribute__((ext_vector_type(4)));

static __device__ __forceinline__ u16 f2bf(float f) {
    union { float f; unsigned int u; } x; x.f = f;
    unsigned int u = x.u;
    return (u16)((u + 0x7FFFu + ((u >> 16) & 1u)) >> 16);  // RNE
}
static __device__ __forceinline__ float bf2f(u16 h) {
    union { unsigned int u; float f; } x; x.u = ((unsigned int)h) << 16;
    return x.f;
}

// Load one MFMA A/B fragment (8 bf16): elems 0-3 at k, elems 4-7 at k+16.
static __device__ __forceinline__ bf16x8 ldfrag(const u16* p) {
    us4 lo = *(const us4*)p;
    us4 hi = *(const us4*)(p + 16);
    bf16x8 a;
    a[0] = (short)lo[0]; a[1] = (short)lo[1]; a[2] = (short)lo[2]; a[3] = (short)lo[3];
    a[4] = (short)hi[0]; a[5] = (short)hi[1]; a[6] = (short)hi[2]; a[7] = (short)hi[3];
    return a;
}

// ---------------- K0: transpose + convert weights to bf16 --------------------
// WT1[j][a]  = gating_w[a*256+j]      (j = h*32+v)
// WT2[o][j]  = output_w[j*256+o]
// WKVT[n][a] = n<32 ? key_w[a*32+n] : value_w[a*32+(n-32)]
__global__ void k0_prep(const float* __restrict__ gating_w,
                        const float* __restrict__ output_w,
                        const float* __restrict__ key_w,
                        const float* __restrict__ value_w,
                        u16* __restrict__ WT1, u16* __restrict__ WT2,
                        u16* __restrict__ WKVT) {
    int i = blockIdx.x * 256 + threadIdx.x;
    if (i < 65536) {
        int a = i >> 8, j = i & 255;
        WT1[j * 256 + a] = f2bf(gating_w[i]);
    } else if (i < 131072) {
        int i2 = i - 65536; int j = i2 >> 8, o = i2 & 255;
        WT2[o * 256 + j] = f2bf(output_w[i2]);
    } else if (i < 139264) {
        int i2 = i - 131072; int a = i2 >> 5, n = i2 & 31;
        WKVT[n * 256 + a] = f2bf(key_w[i2]);
    } else if (i < 147456) {
        int i2 = i - 139264; int a = i2 >> 5, n = i2 & 31;
        WKVT[(32 + n) * 256 + a] = f2bf(value_w[i2]);
    }
}

// ---------------- K1a: masked sum over N -> qsum[b,c], msum[b] --------------
__global__ __launch_bounds__(256) void k1a_qsum(const float* __restrict__ qd,
                                                const float* __restrict__ qmask,
                                                float* __restrict__ qsum,
                                                float* __restrict__ msum) {
    int b = blockIdx.x >> 3, ch = blockIdx.x & 7;
    int t = threadIdx.x;
    __shared__ float ml[256];
    int n0 = b * 2048 + ch * 256;
    ml[t] = qmask[n0 + t];
    __syncthreads();
    float acc = 0.f;
    for (int r = 0; r < 256; ++r)
        acc += ml[r] * qd[(long)(n0 + r) * 256 + t];
    atomicAdd(&qsum[b * 256 + t], acc);
    __syncthreads();
    for (int s = 128; s > 0; s >>= 1) {
        if (t < s) ml[t] += ml[t + s];
        __syncthreads();
    }
    if (t == 0) atomicAdd(&msum[b], ml[0]);
}

// ---------------- K1b: q projection -----------------------------------------
__global__ __launch_bounds__(256) void k1b_qproj(const float* __restrict__ qsum,
                                                 const float* __restrict__ msum,
                                                 const float* __restrict__ query_w,
                                                 float* __restrict__ qproj) {
    int b = blockIdx.x, t = threadIdx.x;
    __shared__ float sq[256];
    float denom = msum[b] + 1e-10f;
    sq[t] = qsum[b * 256 + t] / denom;
    __syncthreads();
    float acc = 0.f;
    for (int c = 0; c < 256; ++c)
        acc += sq[c] * query_w[c * 256 + t];
    qproj[b * 256 + t] = acc * 0.17677669529663687f;  // 32^-0.5
}

// ---------------- K2: k,v projection via MFMA -------------------------------
#define MS_STR 260
__global__ __launch_bounds__(256) void k2_kv(const float* __restrict__ md,
                                             const u16* __restrict__ WKVT,
                                             u16* __restrict__ kk,
                                             u16* __restrict__ vv) {
    __shared__ u16 ms[64 * MS_STR];
    int t = threadIdx.x;
    long base = (long)blockIdx.x * 64;
    const float4* md4 = (const float4*)md + base * 64;
    for (int i = t; i < 4096; i += 256) {
        int r = i >> 6, c4 = i & 63;
        float4 v = md4[r * 64 + c4];
        us4 u; u[0] = f2bf(v.x); u[1] = f2bf(v.y); u[2] = f2bf(v.z); u[3] = f2bf(v.w);
        *(us4*)&ms[r * MS_STR + c4 * 4] = u;
    }
    __syncthreads();
    int w = t >> 6, l = t & 63, lg = l >> 4, ln = l & 15;
    int m0 = w * 16;
    f32x4 acc[4] = {};
#pragma unroll
    for (int ks = 0; ks < 8; ++ks) {
        int k0 = ks * 32;
        bf16x8 a = ldfrag(&ms[(m0 + ln) * MS_STR + k0 + 4 * lg]);
#pragma unroll
        for (int nt = 0; nt < 4; ++nt) {
            bf16x8 bb = ldfrag(&WKVT[(nt * 16 + ln) * 256 + k0 + 4 * lg]);
            acc[nt] = __builtin_amdgcn_mfma_f32_16x16x32_bf16(a, bb, acc[nt], 0, 0, 0);
        }
    }
#pragma unroll
    for (int nt = 0; nt < 4; ++nt) {
        int n = nt * 16 + ln;
#pragma unroll
        for (int rr = 0; rr < 4; ++rr) {
            long row = base + m0 + lg * 4 + rr;
            u16 vb = f2bf(acc[nt][rr]);
            if (n < 32) kk[row * 32 + n] = vb;
            else        vv[row * 32 + (n - 32)] = vb;
        }
    }
}

// ---------------- K3: pooled-query attention per (b,h) ----------------------
__global__ __launch_bounds__(256) void k3_attn(const float* __restrict__ qproj,
                                               const u16* __restrict__ kk,
                                               const u16* __restrict__ vv,
                                               const float* __restrict__ qmask,
                                               float* __restrict__ wa) {
    int b = blockIdx.x >> 3, h = blockIdx.x & 7;
    int t = threadIdx.x;
    __shared__ float qh[32];
    __shared__ float red[256];
    __shared__ float vred[256 * 33];
    if (t < 32) qh[t] = qproj[b * 256 + h * 32 + t];
    __syncthreads();
    float er[8];
    float lmax = -1e30f;
#pragma unroll
    for (int i = 0; i < 8; ++i) {
        int n = t + i * 256;
        const us4* kr = (const us4*)(kk + (size_t)(b * 2048 + n) * 32);
        float acc = 1e9f * (qmask[b * 2048 + n] - 1.0f);
#pragma unroll
        for (int j = 0; j < 8; ++j) {
            us4 u = kr[j];
            acc += qh[j * 4 + 0] * bf2f(u[0]) + qh[j * 4 + 1] * bf2f(u[1])
                 + qh[j * 4 + 2] * bf2f(u[2]) + qh[j * 4 + 3] * bf2f(u[3]);
        }
        er[i] = acc;
        lmax = fmaxf(lmax, acc);
    }
    red[t] = lmax; __syncthreads();
    for (int s = 128; s > 0; s >>= 1) {
        if (t < s) red[t] = fmaxf(red[t], red[t + s]);
        __syncthreads();
    }
    float M = red[0];
    __syncthreads();
    float esum = 0.f;
#pragma unroll
    for (int i = 0; i < 8; ++i) { er[i] = expf(er[i] - M); esum += er[i]; }
    red[t] = esum; __syncthreads();
    for (int s = 128; s > 0; s >>= 1) {
        if (t < s) red[t] += red[t + s];
        __syncthreads();
    }
    float S = red[0];
    __syncthreads();
    float vacc[32];
#pragma unroll
    for (int j = 0; j < 32; ++j) vacc[j] = 0.f;
#pragma unroll
    for (int i = 0; i < 8; ++i) {
        int n = t + i * 256;
        const us4* vr = (const us4*)(vv + (size_t)(b * 2048 + n) * 32);
        float wgt = er[i];
#pragma unroll
        for (int j = 0; j < 8; ++j) {
            us4 u = vr[j];
            vacc[j * 4 + 0] += wgt * bf2f(u[0]);
            vacc[j * 4 + 1] += wgt * bf2f(u[1]);
            vacc[j * 4 + 2] += wgt * bf2f(u[2]);
            vacc[j * 4 + 3] += wgt * bf2f(u[3]);
        }
    }
#pragma unroll
    for (int j = 0; j < 32; ++j) vred[t * 33 + j] = vacc[j];
    __syncthreads();
    for (int s = 128; s > 0; s >>= 1) {
        if (t < s) {
#pragma unroll
            for (int j = 0; j < 32; ++j) vred[t * 33 + j] += vred[(t + s) * 33 + j];
        }
        __syncthreads();
    }
    if (t < 32) wa[b * 256 + h * 32 + t] = vred[t] / S;
}

// ---------------- K4: fused gating GEMM + sigmoid + output GEMM -------------
#define QSTR 260
__global__ __launch_bounds__(256) void k4_out(const float* __restrict__ qd,
                                              const u16* __restrict__ WT1,
                                              const u16* __restrict__ WT2,
                                              const float* __restrict__ wa,
                                              const float* __restrict__ gating_b,
                                              const float* __restrict__ output_b,
                                              float* __restrict__ out) {
    __shared__ u16 qs[64 * QSTR];   // Q tile (phase A), then P tile (phase C)
    int t = threadIdx.x;
    long base = (long)blockIdx.x * 64;
    int b = blockIdx.x >> 5;        // 32 blocks per batch (2048/64)
    // stage Q tile as bf16
    const float4* q4 = (const float4*)qd + base * 64;
    for (int i = t; i < 4096; i += 256) {
        int r = i >> 6, c4 = i & 63;
        float4 v = q4[r * 64 + c4];
        us4 u; u[0] = f2bf(v.x); u[1] = f2bf(v.y); u[2] = f2bf(v.z); u[3] = f2bf(v.w);
        *(us4*)&qs[r * QSTR + c4 * 4] = u;
    }
    __syncthreads();
    int w = t >> 6, l = t & 63, lg = l >> 4, ln = l & 15;

    // Phase A: GL = Q @ W1 ; wave w owns cols [w*64, w*64+64)
    f32x4 acc[4][4] = {};
#pragma unroll
    for (int ks = 0; ks < 8; ++ks) {
        int k0 = ks * 32;
        bf16x8 a[4];
#pragma unroll
        for (int mt = 0; mt < 4; ++mt)
            a[mt] = ldfrag(&qs[(mt * 16 + ln) * QSTR + k0 + 4 * lg]);
#pragma unroll
        for (int nt = 0; nt < 4; ++nt) {
            int col = w * 64 + nt * 16 + ln;
            bf16x8 bb = ldfrag(&WT1[col * 256 + k0 + 4 * lg]);
#pragma unroll
            for (int mt = 0; mt < 4; ++mt)
                acc[mt][nt] = __builtin_amdgcn_mfma_f32_16x16x32_bf16(a[mt], bb, acc[mt][nt], 0, 0, 0);
        }
    }
    __syncthreads();  // everyone done reading Q tile

    // Phase B: P = wa * sigmoid(GL + gb), written to LDS as bf16
#pragma unroll
    for (int nt = 0; nt < 4; ++nt) {
        int col = w * 64 + nt * 16 + ln;
        float gb = gating_b[col];
        float wv = wa[b * 256 + col];
#pragma unroll
        for (int mt = 0; mt < 4; ++mt) {
#pragma unroll
            for (int rr = 0; rr < 4; ++rr) {
                float x = acc[mt][nt][rr];
                float gt = 1.0f / (1.0f + expf(-(x + gb)));
                int row = mt * 16 + lg * 4 + rr;
                qs[row * QSTR + col] = f2bf(wv * gt);
            }
        }
    }
    __syncthreads();

    // Phase C: OUT = P @ W2
    f32x4 acc2[4][4] = {};
#pragma unroll
    for (int ks = 0; ks < 8; ++ks) {
        int k0 = ks * 32;
        bf16x8 a[4];
#pragma unroll
        for (int mt = 0; mt < 4; ++mt)
            a[mt] = ldfrag(&qs[(mt * 16 + ln) * QSTR + k0 + 4 * lg]);
#pragma unroll
        for (int nt = 0; nt < 4; ++nt) {
            int o = w * 64 + nt * 16 + ln;
            bf16x8 bb = ldfrag(&WT2[o * 256 + k0 + 4 * lg]);
#pragma unroll
            for (int mt = 0; mt < 4; ++mt)
                acc2[mt][nt] = __builtin_amdgcn_mfma_f32_16x16x32_bf16(a[mt], bb, acc2[mt][nt], 0, 0, 0);
        }
    }
#pragma unroll
    for (int nt = 0; nt < 4; ++nt) {
        int o = w * 64 + nt * 16 + ln;
        float ob = output_b[o];
#pragma unroll
        for (int mt = 0; mt < 4; ++mt) {
#pragma unroll
            for (int rr = 0; rr < 4; ++rr) {
                long row = base + mt * 16 + lg * 4 + rr;
                out[row * 256 + o] = acc2[mt][nt][rr] + ob;
            }
        }
    }
}

// ---------------- launch ----------------------------------------------------
extern "C" void kernel_launch(void* const* d_in, const int* in_sizes, int n_in,
                              void* d_out, int out_size, void* d_ws, size_t ws_size,
                              hipStream_t stream) {
    const float* q_data   = (const float*)d_in[0];
    const float* m_data   = (const float*)d_in[1];
    const float* q_mask   = (const float*)d_in[2];
    // d_in[3] = bias (unused by reference)
    const float* query_w  = (const float*)d_in[4];
    const float* key_w    = (const float*)d_in[5];
    const float* value_w  = (const float*)d_in[6];
    const float* gating_w = (const float*)d_in[7];
    const float* gating_b = (const float*)d_in[8];
    const float* output_w = (const float*)d_in[9];
    const float* output_b = (const float*)d_in[10];
    float* out = (float*)d_out;

    char* ws = (char*)d_ws;
    u16*   WT1   = (u16*)(ws);                    // 131072 B
    u16*   WT2   = (u16*)(ws + 131072);           // 131072 B
    u16*   WKVT  = (u16*)(ws + 262144);           // 32768 B
    float* qsum  = (float*)(ws + 294912);         // 131072 B
    float* msum  = (float*)(ws + 425984);         // 512 B
    float* qproj = (float*)(ws + 426496);         // 131072 B
    float* wa    = (float*)(ws + 557568);         // 131072 B
    u16*   kk    = (u16*)(ws + 688640);           // 16777216 B
    u16*   vv    = (u16*)(ws + 688640 + 16777216);// 16777216 B

    hipMemsetAsync(ws + 294912, 0, 131584, stream);  // qsum + msum
    k0_prep<<<576, 256, 0, stream>>>(gating_w, output_w, key_w, value_w, WT1, WT2, WKVT);
    k1a_qsum<<<1024, 256, 0, stream>>>(q_data, q_mask, qsum, msum);
    k1b_qproj<<<128, 256, 0, stream>>>(qsum, msum, query_w, qproj);
    k2_kv<<<4096, 256, 0, stream>>>(m_data, WKVT, kk, vv);
    k3_attn<<<1024, 256, 0, stream>>>(qproj, kk, vv, q_mask, wa);
    k4_out<<<4096, 256, 0, stream>>>(q_data, WT1, WT2, wa, gating_b, output_b, out);
}

// Round 8
// 864.519 us; speedup vs baseline: 1.2231x; 1.2231x over previous
//
#include <hip/hip_runtime.h>
#include <hip/hip_bf16.h>
#include <math.h>

// B=128, N=2048, C=256, H=8, KD=VD=32, OUT=256
// Output fp32 [B,N,OUT]

typedef unsigned short u16;
typedef u16 us4 __attribute__((ext_vector_type(4)));
typedef short bf16x8 __attribute__((ext_vector_type(8)));
typedef float f32x4 __attribute__((ext_vector_type(4)));

static __device__ __forceinline__ u16 f2bf(float f) {
    union { float f; unsigned int u; } x; x.f = f;
    unsigned int u = x.u;
    return (u16)((u + 0x7FFFu + ((u >> 16) & 1u)) >> 16);  // RNE
}
static __device__ __forceinline__ float bf2f(u16 h) {
    union { unsigned int u; float f; } x; x.u = ((unsigned int)h) << 16;
    return x.f;
}

// Fragment-major storage: frag block = 1024B; lane l (ln=l&15, lg=l>>4) holds
// 16B: [M[r0+ln][k0+4lg .. +3], M[r0+ln][k0+16+4lg .. +3]]
static __device__ __forceinline__ bf16x8 ldfrag(const u16* p) {
    union { bf16x8 v; struct { us4 lo, hi; } s; } u;
    u.s.lo = *(const us4*)p;
    u.s.hi = *(const us4*)(p + 16);
    return u.v;
}

// ---------------- K0: weights -> bf16, fragment-major ------------------------
__global__ void k0_prep(const float* __restrict__ gating_w,
                        const float* __restrict__ output_w,
                        const float* __restrict__ key_w,
                        const float* __restrict__ value_w,
                        u16* __restrict__ W1F, u16* __restrict__ W2F,
                        u16* __restrict__ WKVTF) {
    int i = blockIdx.x * 256 + threadIdx.x;
    if (i < 131072) {
        int e = i & 65535;
        int frag = e >> 9, l = (e >> 3) & 63, j = e & 7;
        int ln = l & 15, lg = l >> 4, half = j >> 2, jj = j & 3;
        int col = ((frag >> 3) << 4) + ln;                    // w*64+nt*16+ln
        int k   = ((frag & 7) << 5) + (half << 4) + (lg << 2) + jj;
        const float* src = (i < 65536) ? gating_w : output_w; // both [k][col] flat k*256+col
        u16* dst = (i < 65536) ? W1F : W2F;
        dst[e] = f2bf(src[k * 256 + col]);
    } else if (i < 147456) {
        int e = i - 131072;
        int frag = e >> 9, l = (e >> 3) & 63, j = e & 7;
        int ln = l & 15, lg = l >> 4, half = j >> 2, jj = j & 3;
        int n = ((frag >> 3) << 4) + ln;                      // nt*16+ln  (0..63)
        int k = ((frag & 7) << 5) + (half << 4) + (lg << 2) + jj;
        WKVTF[e] = f2bf(n < 32 ? key_w[k * 32 + n] : value_w[k * 32 + (n - 32)]);
    }
}

// ---------------- K1a (primary): q_data -> qbfF frag-major + masked sums ----
#define TS_STR 260
__global__ __launch_bounds__(256) void k1a_fuse(const float* __restrict__ qd,
                                                const float* __restrict__ qmask,
                                                u16* __restrict__ qbfF,
                                                float* __restrict__ qsum,
                                                float* __restrict__ msum) {
    __shared__ float ml[256];
    __shared__ u16 ts[64 * TS_STR];
    __shared__ float csum[4][256];
    int t = threadIdx.x;
    int b = blockIdx.x >> 3, chunk = blockIdx.x & 7;
    int n0 = b * 2048 + chunk * 256;
    ml[t] = qmask[n0 + t];
    int rl = t >> 6, c4 = t & 63;
    float a0 = 0.f, a1 = 0.f, a2 = 0.f, a3 = 0.f;
    const float4* qd4 = (const float4*)qd;
    us4* qbf4 = (us4*)qbfF;
    __syncthreads();
    for (int sub = 0; sub < 4; ++sub) {
        us4 myv[16];
#pragma unroll
        for (int j = 0; j < 16; ++j) {
            int row = j * 4 + rl;                       // 0..63 within sub-tile
            float4 v = qd4[(size_t)(n0 + sub * 64 + row) * 64 + c4];
            float m = ml[sub * 64 + row];
            a0 += m * v.x; a1 += m * v.y; a2 += m * v.z; a3 += m * v.w;
            us4 u; u[0] = f2bf(v.x); u[1] = f2bf(v.y); u[2] = f2bf(v.z); u[3] = f2bf(v.w);
            myv[j] = u;
        }
        __syncthreads();   // previous frag-pass done reading ts
#pragma unroll
        for (int j = 0; j < 16; ++j) {
            int row = j * 4 + rl;
            *(us4*)&ts[row * TS_STR + c4 * 4] = myv[j];
        }
        __syncthreads();
        int tile = blockIdx.x * 4 + sub;
#pragma unroll
        for (int j = 0; j < 16; ++j) {
            int u = j * 256 + t;                        // us4 index within 4096/tile
            int frag = u >> 7, l = (u >> 1) & 63, half = u & 1;
            int ln = l & 15, lg = l >> 4, mt = frag >> 3, ks = frag & 7;
            int srow = mt * 16 + ln;
            int scol = ks * 32 + half * 16 + lg * 4;
            qbf4[(size_t)tile * 4096 + u] = *(const us4*)&ts[srow * TS_STR + scol];
        }
    }
    csum[rl][c4 * 4 + 0] = a0; csum[rl][c4 * 4 + 1] = a1;
    csum[rl][c4 * 4 + 2] = a2; csum[rl][c4 * 4 + 3] = a3;
    __syncthreads();
    float s = csum[0][t] + csum[1][t] + csum[2][t] + csum[3][t];
    atomicAdd(&qsum[b * 256 + t], s);
    for (int st = 128; st > 0; st >>= 1) {
        if (t < st) ml[t] += ml[t + st];
        __syncthreads();
    }
    if (t == 0) atomicAdd(&msum[b], ml[0]);
}

// ---------------- K1a (fallback): masked sums only --------------------------
__global__ __launch_bounds__(256) void k1a_qsum(const float* __restrict__ qd,
                                                const float* __restrict__ qmask,
                                                float* __restrict__ qsum,
                                                float* __restrict__ msum) {
    int b = blockIdx.x >> 3, ch = blockIdx.x & 7;
    int t = threadIdx.x;
    __shared__ float ml[256];
    int n0 = b * 2048 + ch * 256;
    ml[t] = qmask[n0 + t];
    __syncthreads();
    float acc = 0.f;
    for (int r = 0; r < 256; ++r)
        acc += ml[r] * qd[(long)(n0 + r) * 256 + t];
    atomicAdd(&qsum[b * 256 + t], acc);
    __syncthreads();
    for (int s = 128; s > 0; s >>= 1) {
        if (t < s) ml[t] += ml[t + s];
        __syncthreads();
    }
    if (t == 0) atomicAdd(&msum[b], ml[0]);
}

// ---------------- K1b: q projection -----------------------------------------
__global__ __launch_bounds__(256) void k1b_qproj(const float* __restrict__ qsum,
                                                 const float* __restrict__ msum,
                                                 const float* __restrict__ query_w,
                                                 float* __restrict__ qproj) {
    int b = blockIdx.x, t = threadIdx.x;
    __shared__ float sq[256];
    float denom = msum[b] + 1e-10f;
    sq[t] = qsum[b * 256 + t] / denom;
    __syncthreads();
    float acc = 0.f;
    for (int c = 0; c < 256; ++c)
        acc += sq[c] * query_w[c * 256 + t];
    qproj[b * 256 + t] = acc * 0.17677669529663687f;  // 32^-0.5
}

// ---------------- K2: k,v projection via MFMA -------------------------------
#define MS_STR 260
__global__ __launch_bounds__(256) void k2_kv(const float* __restrict__ md,
                                             const u16* __restrict__ WKVTF,
                                             u16* __restrict__ kk,
                                             u16* __restrict__ vv) {
    __shared__ u16 ms[64 * MS_STR];
    int t = threadIdx.x;
    long base = (long)blockIdx.x * 64;
    const float4* md4 = (const float4*)md + base * 64;
    for (int i = t; i < 4096; i += 256) {
        int r = i >> 6, c4 = i & 63;
        float4 v = md4[r * 64 + c4];
        us4 u; u[0] = f2bf(v.x); u[1] = f2bf(v.y); u[2] = f2bf(v.z); u[3] = f2bf(v.w);
        *(us4*)&ms[r * MS_STR + c4 * 4] = u;
    }
    __syncthreads();
    int w = t >> 6, l = t & 63, lg = l >> 4, ln = l & 15;
    int m0 = w * 16;
    const bf16x8* wkv = (const bf16x8*)WKVTF;
    f32x4 acc[4] = {};
#pragma unroll
    for (int ks = 0; ks < 8; ++ks) {
        int k0 = ks * 32;
        bf16x8 a = ldfrag(&ms[(m0 + ln) * MS_STR + k0 + 4 * lg]);
#pragma unroll
        for (int nt = 0; nt < 4; ++nt) {
            bf16x8 bb = wkv[(nt * 8 + ks) * 64 + l];
            acc[nt] = __builtin_amdgcn_mfma_f32_16x16x32_bf16(a, bb, acc[nt], 0, 0, 0);
        }
    }
#pragma unroll
    for (int nt = 0; nt < 4; ++nt) {
        int n = nt * 16 + ln;
#pragma unroll
        for (int rr = 0; rr < 4; ++rr) {
            long row = base + m0 + lg * 4 + rr;
            u16 vb = f2bf(acc[nt][rr]);
            if (n < 32) kk[row * 32 + n] = vb;
            else        vv[row * 32 + (n - 32)] = vb;
        }
    }
}

// ---------------- K3: pooled-query attention per (b,h) ----------------------
__global__ __launch_bounds__(256) void k3_attn(const float* __restrict__ qproj,
                                               const u16* __restrict__ kk,
                                               const u16* __restrict__ vv,
                                               const float* __restrict__ qmask,
                                               float* __restrict__ wa) {
    int b = blockIdx.x >> 3, h = blockIdx.x & 7;
    int t = threadIdx.x;
    __shared__ float qh[32];
    __shared__ float red[256];
    __shared__ float vred[256 * 33];
    if (t < 32) qh[t] = qproj[b * 256 + h * 32 + t];
    __syncthreads();
    float er[8];
    float lmax = -1e30f;
#pragma unroll
    for (int i = 0; i < 8; ++i) {
        int n = t + i * 256;
        const us4* kr = (const us4*)(kk + (size_t)(b * 2048 + n) * 32);
        float acc = 1e9f * (qmask[b * 2048 + n] - 1.0f);
#pragma unroll
        for (int j = 0; j < 8; ++j) {
            us4 u = kr[j];
            acc += qh[j * 4 + 0] * bf2f(u[0]) + qh[j * 4 + 1] * bf2f(u[1])
                 + qh[j * 4 + 2] * bf2f(u[2]) + qh[j * 4 + 3] * bf2f(u[3]);
        }
        er[i] = acc;
        lmax = fmaxf(lmax, acc);
    }
    red[t] = lmax; __syncthreads();
    for (int s = 128; s > 0; s >>= 1) {
        if (t < s) red[t] = fmaxf(red[t], red[t + s]);
        __syncthreads();
    }
    float M = red[0];
    __syncthreads();
    float esum = 0.f;
#pragma unroll
    for (int i = 0; i < 8; ++i) { er[i] = __expf(er[i] - M); esum += er[i]; }
    red[t] = esum; __syncthreads();
    for (int s = 128; s > 0; s >>= 1) {
        if (t < s) red[t] += red[t + s];
        __syncthreads();
    }
    float S = red[0];
    __syncthreads();
    float vacc[32];
#pragma unroll
    for (int j = 0; j < 32; ++j) vacc[j] = 0.f;
#pragma unroll
    for (int i = 0; i < 8; ++i) {
        int n = t + i * 256;
        const us4* vr = (const us4*)(vv + (size_t)(b * 2048 + n) * 32);
        float wgt = er[i];
#pragma unroll
        for (int j = 0; j < 8; ++j) {
            us4 u = vr[j];
            vacc[j * 4 + 0] += wgt * bf2f(u[0]);
            vacc[j * 4 + 1] += wgt * bf2f(u[1]);
            vacc[j * 4 + 2] += wgt * bf2f(u[2]);
            vacc[j * 4 + 3] += wgt * bf2f(u[3]);
        }
    }
#pragma unroll
    for (int j = 0; j < 32; ++j) vred[t * 33 + j] = vacc[j];
    __syncthreads();
    for (int s = 128; s > 0; s >>= 1) {
        if (t < s) {
#pragma unroll
            for (int j = 0; j < 32; ++j) vred[t * 33 + j] += vred[(t + s) * 33 + j];
        }
        __syncthreads();
    }
    if (t < 32) wa[b * 256 + h * 32 + t] = vred[t] / S;
}

// ---------------- K4 (primary): frag-major A from qbfF, 1 barrier -----------
#define PSTR 264
__global__ __launch_bounds__(256) void k4_out(const u16* __restrict__ qbfF,
                                              const u16* __restrict__ W1F,
                                              const u16* __restrict__ W2F,
                                              const float* __restrict__ wa,
                                              const float* __restrict__ gating_b,
                                              const float* __restrict__ output_b,
                                              float* __restrict__ out) {
    __shared__ u16 ps[64 * PSTR];
    int t = threadIdx.x;
    int tile = blockIdx.x;            // 4096 tiles of 64 rows
    int b = tile >> 5;
    int w = t >> 6, l = t & 63, lg = l >> 4, ln = l & 15;
    const bf16x8* qa = (const bf16x8*)(qbfF + (size_t)tile * 16384);
    const bf16x8* w1 = (const bf16x8*)W1F;
    const bf16x8* w2 = (const bf16x8*)W2F;

    // Phase A: GL = Q @ W1
    f32x4 acc[4][4] = {};
#pragma unroll
    for (int ks = 0; ks < 8; ++ks) {
        bf16x8 a[4];
#pragma unroll
        for (int mt = 0; mt < 4; ++mt)
            a[mt] = qa[(mt * 8 + ks) * 64 + l];
#pragma unroll
        for (int nt = 0; nt < 4; ++nt) {
            bf16x8 bb = w1[((w * 4 + nt) * 8 + ks) * 64 + l];
#pragma unroll
            for (int mt = 0; mt < 4; ++mt)
                acc[mt][nt] = __builtin_amdgcn_mfma_f32_16x16x32_bf16(a[mt], bb, acc[mt][nt], 0, 0, 0);
        }
    }

    // Phase B: P = wa * sigmoid(GL + gb) -> LDS (bf16)
#pragma unroll
    for (int nt = 0; nt < 4; ++nt) {
        int col = w * 64 + nt * 16 + ln;
        float gb = gating_b[col];
        float wv = wa[b * 256 + col];
#pragma unroll
        for (int mt = 0; mt < 4; ++mt) {
#pragma unroll
            for (int rr = 0; rr < 4; ++rr) {
                float x = acc[mt][nt][rr] + gb;
                float e = __expf(-x);
                float p = wv * __builtin_amdgcn_rcpf(1.0f + e);
                ps[(mt * 16 + lg * 4 + rr) * PSTR + col] = f2bf(p);
            }
        }
    }
    __syncthreads();

    // Phase C: OUT = P @ W2
    f32x4 acc2[4][4] = {};
#pragma unroll
    for (int ks = 0; ks < 8; ++ks) {
        bf16x8 a[4];
#pragma unroll
        for (int mt = 0; mt < 4; ++mt)
            a[mt] = ldfrag(&ps[(mt * 16 + ln) * PSTR + ks * 32 + 4 * lg]);
#pragma unroll
        for (int nt = 0; nt < 4; ++nt) {
            bf16x8 bb = w2[((w * 4 + nt) * 8 + ks) * 64 + l];
#pragma unroll
            for (int mt = 0; mt < 4; ++mt)
                acc2[mt][nt] = __builtin_amdgcn_mfma_f32_16x16x32_bf16(a[mt], bb, acc2[mt][nt], 0, 0, 0);
        }
    }
#pragma unroll
    for (int nt = 0; nt < 4; ++nt) {
        int o = w * 64 + nt * 16 + ln;
        float ob = output_b[o];
#pragma unroll
        for (int mt = 0; mt < 4; ++mt) {
#pragma unroll
            for (int rr = 0; rr < 4; ++rr) {
                size_t row = (size_t)tile * 64 + mt * 16 + lg * 4 + rr;
                out[row * 256 + o] = acc2[mt][nt][rr] + ob;
            }
        }
    }
}

// ---------------- K4 (fallback): stage fp32 q_data in LDS, frag weights -----
__global__ __launch_bounds__(256) void k4_stage(const float* __restrict__ qd,
                                                const u16* __restrict__ W1F,
                                                const u16* __restrict__ W2F,
                                                const float* __restrict__ wa,
                                                const float* __restrict__ gating_b,
                                                const float* __restrict__ output_b,
                                                float* __restrict__ out) {
    __shared__ u16 qs[64 * PSTR];   // Q tile (phase A), then P tile (phase C)
    int t = threadIdx.x;
    int tile = blockIdx.x;
    long base = (long)tile * 64;
    int b = tile >> 5;
    const float4* q4 = (const float4*)qd + base * 64;
    for (int i = t; i < 4096; i += 256) {
        int r = i >> 6, c4 = i & 63;
        float4 v = q4[r * 64 + c4];
        us4 u; u[0] = f2bf(v.x); u[1] = f2bf(v.y); u[2] = f2bf(v.z); u[3] = f2bf(v.w);
        *(us4*)&qs[r * PSTR + c4 * 4] = u;
    }
    __syncthreads();
    int w = t >> 6, l = t & 63, lg = l >> 4, ln = l & 15;
    const bf16x8* w1 = (const bf16x8*)W1F;
    const bf16x8* w2 = (const bf16x8*)W2F;

    f32x4 acc[4][4] = {};
#pragma unroll
    for (int ks = 0; ks < 8; ++ks) {
        bf16x8 a[4];
#pragma unroll
        for (int mt = 0; mt < 4; ++mt)
            a[mt] = ldfrag(&qs[(mt * 16 + ln) * PSTR + ks * 32 + 4 * lg]);
#pragma unroll
        for (int nt = 0; nt < 4; ++nt) {
            bf16x8 bb = w1[((w * 4 + nt) * 8 + ks) * 64 + l];
#pragma unroll
            for (int mt = 0; mt < 4; ++mt)
                acc[mt][nt] = __builtin_amdgcn_mfma_f32_16x16x32_bf16(a[mt], bb, acc[mt][nt], 0, 0, 0);
        }
    }
    __syncthreads();  // done reading Q tile

#pragma unroll
    for (int nt = 0; nt < 4; ++nt) {
        int col = w * 64 + nt * 16 + ln;
        float gb = gating_b[col];
        float wv = wa[b * 256 + col];
#pragma unroll
        for (int mt = 0; mt < 4; ++mt) {
#pragma unroll
            for (int rr = 0; rr < 4; ++rr) {
                float x = acc[mt][nt][rr] + gb;
                float e = __expf(-x);
                float p = wv * __builtin_amdgcn_rcpf(1.0f + e);
                qs[(mt * 16 + lg * 4 + rr) * PSTR + col] = f2bf(p);
            }
        }
    }
    __syncthreads();

    f32x4 acc2[4][4] = {};
#pragma unroll
    for (int ks = 0; ks < 8; ++ks) {
        bf16x8 a[4];
#pragma unroll
        for (int mt = 0; mt < 4; ++mt)
            a[mt] = ldfrag(&qs[(mt * 16 + ln) * PSTR + ks * 32 + 4 * lg]);
#pragma unroll
        for (int nt = 0; nt < 4; ++nt) {
            bf16x8 bb = w2[((w * 4 + nt) * 8 + ks) * 64 + l];
#pragma unroll
            for (int mt = 0; mt < 4; ++mt)
                acc2[mt][nt] = __builtin_amdgcn_mfma_f32_16x16x32_bf16(a[mt], bb, acc2[mt][nt], 0, 0, 0);
        }
    }
#pragma unroll
    for (int nt = 0; nt < 4; ++nt) {
        int o = w * 64 + nt * 16 + ln;
        float ob = output_b[o];
#pragma unroll
        for (int mt = 0; mt < 4; ++mt) {
#pragma unroll
            for (int rr = 0; rr < 4; ++rr) {
                size_t row = base + mt * 16 + lg * 4 + rr;
                out[row * 256 + o] = acc2[mt][nt][rr] + ob;
            }
        }
    }
}

// ---------------- launch ----------------------------------------------------
extern "C" void kernel_launch(void* const* d_in, const int* in_sizes, int n_in,
                              void* d_out, int out_size, void* d_ws, size_t ws_size,
                              hipStream_t stream) {
    const float* q_data   = (const float*)d_in[0];
    const float* m_data   = (const float*)d_in[1];
    const float* q_mask   = (const float*)d_in[2];
    // d_in[3] = bias (unused by reference)
    const float* query_w  = (const float*)d_in[4];
    const float* key_w    = (const float*)d_in[5];
    const float* value_w  = (const float*)d_in[6];
    const float* gating_w = (const float*)d_in[7];
    const float* gating_b = (const float*)d_in[8];
    const float* output_w = (const float*)d_in[9];
    const float* output_b = (const float*)d_in[10];
    float* out = (float*)d_out;

    char* ws = (char*)d_ws;
    u16*   W1F   = (u16*)(ws);                          // 131072 B
    u16*   W2F   = (u16*)(ws + 131072);                 // 131072 B
    u16*   WKVTF = (u16*)(ws + 262144);                 // 32768 B
    float* qsum  = (float*)(ws + 294912);               // 131072 B
    float* msum  = (float*)(ws + 425984);               // 512 B
    float* qproj = (float*)(ws + 426496);               // 131072 B
    float* wa    = (float*)(ws + 557568);               // 131072 B
    u16*   kk    = (u16*)(ws + 688640);                 // 16777216 B
    u16*   vv    = (u16*)(ws + 688640 + 16777216);      // 16777216 B
    u16*   qbfF  = (u16*)(ws + 688640 + 2 * 16777216);  // 134217728 B (ends 168460800 B)

    const size_t NEED_BIG = 688640 + 2ull * 16777216 + 134217728;  // ~160.7 MiB
    bool big = ws_size >= NEED_BIG;

    hipMemsetAsync(ws + 294912, 0, 131584, stream);  // qsum + msum
    k0_prep<<<576, 256, 0, stream>>>(gating_w, output_w, key_w, value_w, W1F, W2F, WKVTF);
    if (big) {
        k1a_fuse<<<1024, 256, 0, stream>>>(q_data, q_mask, qbfF, qsum, msum);
    } else {
        k1a_qsum<<<1024, 256, 0, stream>>>(q_data, q_mask, qsum, msum);
    }
    k1b_qproj<<<128, 256, 0, stream>>>(qsum, msum, query_w, qproj);
    k2_kv<<<4096, 256, 0, stream>>>(m_data, WKVTF, kk, vv);
    k3_attn<<<1024, 256, 0, stream>>>(qproj, kk, vv, q_mask, wa);
    if (big) {
        k4_out<<<4096, 256, 0, stream>>>(qbfF, W1F, W2F, wa, gating_b, output_b, out);
    } else {
        k4_stage<<<4096, 256, 0, stream>>>(q_data, W1F, W2F, wa, gating_b, output_b, out);
    }
}